// Round 1
// baseline (653.435 us; speedup 1.0000x reference)
//
#include <hip/hip_runtime.h>

#define S 512
#define NB 8          // batch
#define KT 256        // k-tile per block
#define JT 32         // j-tile per staging round

// Copy the untouched region: out[b,r,c] = x[b,r,c] for r+c >= S.
__global__ __launch_bounds__(256) void tail_copy_kernel(const float* __restrict__ x,
                                                        float* __restrict__ out) {
  int idx = blockIdx.x * 256 + threadIdx.x;
  int c = idx & (S - 1);
  int r = (idx >> 9) & (S - 1);
  if (r + c >= S) out[idx] = x[idx];
}

// One block per (diagonal i, k-tile). Computes out[b, i-k, k] for k in tile.
__global__ __launch_bounds__(256, 3) void diag_linear_kernel(const float* __restrict__ x,
                                                             const float* __restrict__ W,
                                                             const float* __restrict__ bias,
                                                             float* __restrict__ out) {
  // Wt[j][k]: transposed W tile (32 KB). Reused as Racc[b][k] (8 KB) at the end.
  __shared__ __align__(16) float WtBuf[JT * KT];
  // Dl[j][b]: gathered diagonal of x (16 KB).
  __shared__ __align__(16) float DlBuf[S * NB];

  const int i  = (S - 1) - (int)blockIdx.x;   // big diagonals first
  const int k0 = (int)blockIdx.y * KT;
  if (k0 > i) return;                          // uniform exit, before any barrier

  const int tid  = threadIdx.x;
  const int wave = tid >> 6;
  const int lane = tid & 63;

  const int jend = (i + JT) & ~(JT - 1);       // roundup(i+1, JT)

  // ---- stage D: Dl[j][b] = x[b, j, i-j] for j<=i, else 0 (zero-fill padding) ----
  for (int idx = tid; idx < jend * NB; idx += 256) {
    const int j = idx >> 3;
    const int b = idx & 7;
    DlBuf[idx] = (j <= i) ? x[b * (S * S) + j * S + (i - j)] : 0.0f;
  }

  // accumulators: lane owns k-local = 4*lane + m, all 8 batches
  float acc[4][NB];
#pragma unroll
  for (int m = 0; m < 4; ++m)
#pragma unroll
    for (int b = 0; b < NB; ++b) acc[m][b] = 0.0f;

  const int  k       = k0 + tid;               // this thread's W row (loader role)
  const bool krow_ok = (k <= i);               // rows k>i are all-zero: skip HBM reads
  const float* wrow  = W + ((size_t)i * S + k) * S;

  // preload tile 0 (rows with k>i contribute zeros)
  float4 v[8];
#pragma unroll
  for (int q = 0; q < 8; ++q)
    v[q] = krow_ok ? *(const float4*)(wrow + 4 * q)
                   : make_float4(0.f, 0.f, 0.f, 0.f);

  for (int j0 = 0; j0 < jend; j0 += JT) {
    __syncthreads();                           // previous tile's compute done; Wt free
    // transpose-store staged registers: Wt[j_local][k_local]
#pragma unroll
    for (int q = 0; q < 8; ++q) {
      WtBuf[(4 * q + 0) * KT + tid] = v[q].x;
      WtBuf[(4 * q + 1) * KT + tid] = v[q].y;
      WtBuf[(4 * q + 2) * KT + tid] = v[q].z;
      WtBuf[(4 * q + 3) * KT + tid] = v[q].w;
    }
    // software pipeline: issue next tile's global loads before computing this one
    const int jn = j0 + JT;
    if (jn < jend && krow_ok) {
#pragma unroll
      for (int q = 0; q < 8; ++q)
        v[q] = *(const float4*)(wrow + jn + 4 * q);
    }
    __syncthreads();                           // Wt (and Dl on first iter) visible

    // compute: wave handles j_local in [8*wave, 8*wave+8)
#pragma unroll
    for (int u = 0; u < 8; ++u) {
      const int jl = (wave << 3) + u;
      const float4 wv = *(const float4*)&WtBuf[jl * KT + (lane << 2)]; // conflict-free b128
      const float4 dA = *(const float4*)&DlBuf[(j0 + jl) * NB];        // broadcast
      const float4 dB = *(const float4*)&DlBuf[(j0 + jl) * NB + 4];    // broadcast
      const float wm[4] = {wv.x, wv.y, wv.z, wv.w};
#pragma unroll
      for (int m = 0; m < 4; ++m) {
        acc[m][0] = fmaf(wm[m], dA.x, acc[m][0]);
        acc[m][1] = fmaf(wm[m], dA.y, acc[m][1]);
        acc[m][2] = fmaf(wm[m], dA.z, acc[m][2]);
        acc[m][3] = fmaf(wm[m], dA.w, acc[m][3]);
        acc[m][4] = fmaf(wm[m], dB.x, acc[m][4]);
        acc[m][5] = fmaf(wm[m], dB.y, acc[m][5]);
        acc[m][6] = fmaf(wm[m], dB.z, acc[m][6]);
        acc[m][7] = fmaf(wm[m], dB.w, acc[m][7]);
      }
    }
  }

  __syncthreads();                             // all compute done; Wt reusable as Racc
  float* Racc = WtBuf;                         // Racc[b*KT + k_local]

  // cross-wave reduction (waves split j, so each holds partials for all k)
  for (int w = 0; w < 4; ++w) {
    if (wave == w) {
#pragma unroll
      for (int b = 0; b < NB; ++b) {
        float4* p = (float4*)&Racc[b * KT + (lane << 2)];  // conflict-free b128
        float4 cur = make_float4(acc[0][b], acc[1][b], acc[2][b], acc[3][b]);
        if (w != 0) {
          float4 old = *p;
          cur.x += old.x; cur.y += old.y; cur.z += old.z; cur.w += old.w;
        }
        *p = cur;
      }
    }
    __syncthreads();
  }

  // epilogue: bias + scatter out[b, i-k, k]
  if (krow_ok) {
    const float bv = bias[i * S + k];
    const int r = i - k;
#pragma unroll
    for (int b = 0; b < NB; ++b)
      out[b * (S * S) + r * S + k] = Racc[b * KT + tid] + bv;
  }
}

extern "C" void kernel_launch(void* const* d_in, const int* in_sizes, int n_in,
                              void* d_out, int out_size, void* d_ws, size_t ws_size,
                              hipStream_t stream) {
  const float* x    = (const float*)d_in[0];
  const float* W    = (const float*)d_in[1];
  const float* bias = (const float*)d_in[2];
  float* out = (float*)d_out;

  (void)d_ws; (void)ws_size; (void)in_sizes; (void)n_in; (void)out_size;

  tail_copy_kernel<<<dim3((NB * S * S) / 256), 256, 0, stream>>>(x, out);
  diag_linear_kernel<<<dim3(S, 2), 256, 0, stream>>>(x, W, bias, out);
}